// Round 3
// baseline (539.291 us; speedup 1.0000x reference)
//
#include <hip/hip_runtime.h>
#include <hip/hip_bf16.h>
#include <math.h>

#define NN 100000
#define EE 1600000
#define MM 20000
#define NB ((NN + 63) / 64)   // dst buckets of 64 nodes

// ---- tiny: v1[16] = We1 @ a_e1 (64), v2[16] = We2 @ a_e2 (32) ----
__global__ void k_v(const float* __restrict__ We1, const float* __restrict__ ae1v,
                    const float* __restrict__ We2, const float* __restrict__ ae2v,
                    float* __restrict__ v1, float* __restrict__ v2) {
    int t = threadIdx.x;
    if (t < 16) {
        float s = 0.f;
        for (int c = 0; c < 64; ++c) s += We1[t * 64 + c] * ae1v[c];
        v1[t] = s;
    } else if (t < 32) {
        int r = t - 16;
        float s = 0.f;
        for (int c = 0; c < 32; ++c) s += We2[r * 32 + c] * ae2v[c];
        v2[r] = s;
    }
}

// ---- dst-degree histogram ----
__global__ __launch_bounds__(256) void k_deg(const int* __restrict__ dst,
                                             int* __restrict__ deg, int E) {
    int e = blockIdx.x * 256 + threadIdx.x;
    if (e < E) atomicAdd(&deg[dst[e]], 1);
}

// ---- layer-1 node transform: hx1 = x @ W1, alpha_s/d per node; zero deg ----
__global__ __launch_bounds__(256) void k_node1(
    const float* __restrict__ x, const float* __restrict__ W,
    const float* __restrict__ a_s, const float* __restrict__ a_d,
    float* __restrict__ hx, float* __restrict__ aS, float* __restrict__ aD,
    int* __restrict__ deg, int n_nodes)
{
    __shared__ float Wl[64 * 64];
    __shared__ float xs[4][64];
    int tid = threadIdx.x;
#pragma unroll
    for (int i = 0; i < 16; ++i) Wl[tid + i * 256] = W[tid + i * 256];
    int wv = tid >> 6, lane = tid & 63;
    int n = blockIdx.x * 4 + wv;
    bool act = (n < n_nodes);
    if (act) xs[wv][lane] = x[(size_t)n * 64 + lane];
    __syncthreads();
    if (!act) return;
    float h = 0.f;
#pragma unroll
    for (int k = 0; k < 64; ++k) h += xs[wv][k] * Wl[k * 64 + lane];
    hx[(size_t)n * 64 + lane] = h;
    float ps = h * a_s[lane];
    float pd = h * a_d[lane];
#pragma unroll
    for (int o = 32; o > 0; o >>= 1) { ps += __shfl_xor(ps, o); pd += __shfl_xor(pd, o); }
    if (lane == 0) { aS[n] = ps; aD[n] = pd; deg[n] = 0; }
}

// ---- scan kernels: exclusive prefix over deg[0..n) (2048 elems/block) ----
__global__ __launch_bounds__(256) void k_scan1(const int* __restrict__ deg, int* __restrict__ pre,
                                               int* __restrict__ bsum, int n) {
    __shared__ int wsum[4];
    int t = threadIdx.x;
    int base = blockIdx.x * 2048 + t * 8;
    int v[8]; int s = 0;
#pragma unroll
    for (int i = 0; i < 8; ++i) { int idx = base + i; int d = (idx < n) ? deg[idx] : 0; v[i] = s; s += d; }
    int lane = t & 63, wv = t >> 6;
    int incl = s;
#pragma unroll
    for (int off = 1; off < 64; off <<= 1) { int y = __shfl_up(incl, off); if (lane >= off) incl += y; }
    if (lane == 63) wsum[wv] = incl;
    __syncthreads();
    int woff = 0;
    for (int w = 0; w < wv; ++w) woff += wsum[w];
    int texcl = woff + incl - s;
#pragma unroll
    for (int i = 0; i < 8; ++i) { int idx = base + i; if (idx < n) pre[idx] = texcl + v[i]; }
    if (t == 255) bsum[blockIdx.x] = woff + incl;
}

__global__ void k_scan2(int* __restrict__ bsum, int nb) {
    int t = threadIdx.x;
    int x = (t < nb) ? bsum[t] : 0;
    int incl = x;
    for (int off = 1; off < 64; off <<= 1) {
        int y = __shfl_up(incl, off);
        if (t >= off) incl += y;
    }
    if (t < nb) bsum[t] = incl - x;
}

__global__ void k_scan3(int* __restrict__ pre, const int* __restrict__ bsum,
                        int* __restrict__ cur, int* __restrict__ bcur, int n) {
    int i = blockIdx.x * 256 + threadIdx.x;
    if (i < n) {
        int r = pre[i] + bsum[i >> 11];
        pre[i] = r; cur[i] = r;
        if ((i & 63) == 0) bcur[i >> 6] = r;
    }
}

// ---- pass 1: edge dots + exp(alpha1), scatter to 64-node dst buckets ----
__global__ __launch_bounds__(256) void k_scatter1(
    const float* __restrict__ ea, const float* __restrict__ v1, const float* __restrict__ v2,
    const int* __restrict__ src, const int* __restrict__ dst,
    const float* __restrict__ aS1, const float* __restrict__ aD1,
    int* __restrict__ bcur, float4* __restrict__ eSb, int E)
{
    int e = blockIdx.x * 256 + threadIdx.x;
    if (e >= E) return;
    const float* p = ea + (size_t)e * 16;
    float s1 = 0.f, s2 = 0.f;
#pragma unroll
    for (int i = 0; i < 16; ++i) { float t = p[i]; s1 += t * v1[i]; s2 += t * v2[i]; }
    int s = src[e], d = dst[e];
    float a = aS1[s] + aD1[d] + s1;
    a = a > 0.f ? a : 0.2f * a;
    int pos = atomicAdd(&bcur[d >> 6], 1);
    eSb[pos] = make_float4(__int_as_float(s), __int_as_float(d), __expf(a), s2);
}

// ---- pass 2: within-bucket exact CSR placement (writes stay in ~16KB window) ----
__global__ __launch_bounds__(256) void k_scatter2(
    const float4* __restrict__ eSb, const int* __restrict__ rowptr,
    int* __restrict__ cur, float4* __restrict__ eS, int E)
{
    int b = blockIdx.x;
    int start = rowptr[b << 6];
    int nend = (b + 1) << 6;
    int end = (nend >= NN) ? E : rowptr[nend];
    for (int i = start + (int)threadIdx.x; i < end; i += 256) {
        float4 r = eSb[i];
        int d = __float_as_int(r.y);
        int p = atomicAdd(&cur[d], 1);
        eS[p] = make_float4(r.x, r.z, r.w, 0.f);
    }
}

// ---- layer-1 pull aggregation + finalize (self-loop, div, bias, elu) -> h1 ----
__global__ __launch_bounds__(256) void k_agg1(
    const int* __restrict__ rowptr, const int* __restrict__ rowend,
    const float4* __restrict__ eS, const float* __restrict__ hx,
    const float* __restrict__ aS, const float* __restrict__ aD,
    const float* __restrict__ b, float* __restrict__ h1, int n_nodes)
{
    int wv = threadIdx.x >> 6, lane = threadIdx.x & 63;
    int n = blockIdx.x * 4 + wv;
    if (n >= n_nodes) return;
    int start = rowptr[n], end = rowend[n];
    float r = 0.f, den = 0.f;
    for (int base = start; base < end; base += 64) {
        int cnt = min(end - base, 64);
        int s = 0; float ex = 0.f;
        if (lane < cnt) {
            float4 E4 = eS[base + lane];
            s = __float_as_int(E4.x);
            ex = E4.y;
        }
        int j = 0;
        for (; j + 4 <= cnt; j += 4) {
            int s0 = __shfl(s, j), s1 = __shfl(s, j + 1), s2 = __shfl(s, j + 2), s3 = __shfl(s, j + 3);
            float e0 = __shfl(ex, j), e1 = __shfl(ex, j + 1), e2 = __shfl(ex, j + 2), e3 = __shfl(ex, j + 3);
            float h0 = hx[(size_t)s0 * 64 + lane];
            float h1v = hx[(size_t)s1 * 64 + lane];
            float h2 = hx[(size_t)s2 * 64 + lane];
            float h3 = hx[(size_t)s3 * 64 + lane];
            r += e0 * h0; r += e1 * h1v; r += e2 * h2; r += e3 * h3;
            den += e0 + e1 + e2 + e3;
        }
        for (; j < cnt; ++j) {
            int sj = __shfl(s, j); float ej = __shfl(ex, j);
            r += ej * hx[(size_t)sj * 64 + lane];
            den += ej;
        }
    }
    float al = aS[n] + aD[n];
    al = al > 0.f ? al : 0.2f * al;
    float exl = __expf(al);
    float val = (r + exl * hx[(size_t)n * 64 + lane]) / (den + exl) + b[lane];
    h1[(size_t)n * 64 + lane] = val > 0.f ? val : expm1f(val);
}

// ---- layer-2 node transform: hx2 = h1 @ W2 (64->32), alpha_s/d ----
__global__ __launch_bounds__(256) void k_node2(
    const float* __restrict__ h1, const float* __restrict__ W,
    const float* __restrict__ a_s, const float* __restrict__ a_d,
    float* __restrict__ hx, float* __restrict__ aS, float* __restrict__ aD, int n_nodes)
{
    __shared__ float Wl[64 * 32];
    __shared__ float xs[8][64];
    int tid = threadIdx.x;
#pragma unroll
    for (int i = 0; i < 8; ++i) Wl[tid + i * 256] = W[tid + i * 256];
    int n0 = blockIdx.x * 8;
    for (int i = tid; i < 8 * 64; i += 256) {
        int r = i >> 6;
        int n = n0 + r;
        xs[r][i & 63] = (n < n_nodes) ? h1[(size_t)n * 64 + (i & 63)] : 0.f;
    }
    __syncthreads();
    int g = tid >> 5, c = tid & 31;
    int n = n0 + g;
    if (n >= n_nodes) return;
    float h = 0.f;
#pragma unroll
    for (int k = 0; k < 64; ++k) h += xs[g][k] * Wl[k * 32 + c];
    hx[(size_t)n * 32 + c] = h;
    float ps = h * a_s[c], pd = h * a_d[c];
#pragma unroll
    for (int o = 16; o > 0; o >>= 1) { ps += __shfl_xor(ps, o, 32); pd += __shfl_xor(pd, o, 32); }
    if (c == 0) { aS[n] = ps; aD[n] = pd; }
}

// ---- layer-2 pull aggregation over masked nodes only + finalize -> out ----
__global__ __launch_bounds__(256) void k_agg2(
    const int* __restrict__ mask,
    const int* __restrict__ rowptr, const int* __restrict__ rowend,
    const float4* __restrict__ eS, const float* __restrict__ hx,
    const float* __restrict__ aS, const float* __restrict__ aD,
    const float* __restrict__ b, float* __restrict__ out, int m_cnt)
{
    int wv = threadIdx.x >> 6, lane = threadIdx.x & 63;
    int m = blockIdx.x * 4 + wv;
    if (m >= m_cnt) return;
    int n = mask[m];
    int start = rowptr[n], end = rowend[n];
    float aDn = aD[n];
    int half = lane >> 5, c = lane & 31;
    float r = 0.f, den = 0.f;
    for (int base = start; base < end; base += 64) {
        int cnt = min(end - base, 64);
        int s = 0; float ex = 0.f;
        if (lane < cnt) {
            float4 E4 = eS[base + lane];
            s = __float_as_int(E4.x);
            float a = aS[s] + aDn + E4.z;
            a = a > 0.f ? a : 0.2f * a;
            ex = __expf(a);
        }
        int j = 0;
        for (; j + 8 <= cnt; j += 8) {
            int j0 = j + half, j2 = j + 2 + half, j4 = j + 4 + half, j6 = j + 6 + half;
            int s0 = __shfl(s, j0), s2v = __shfl(s, j2), s4 = __shfl(s, j4), s6 = __shfl(s, j6);
            float e0 = __shfl(ex, j0), e2 = __shfl(ex, j2), e4 = __shfl(ex, j4), e6 = __shfl(ex, j6);
            r += e0 * hx[(size_t)s0 * 32 + c];
            r += e2 * hx[(size_t)s2v * 32 + c];
            r += e4 * hx[(size_t)s4 * 32 + c];
            r += e6 * hx[(size_t)s6 * 32 + c];
            den += e0 + e2 + e4 + e6;
        }
        for (; j < cnt; j += 2) {
            int jj = j + half;
            if (jj < cnt) {
                int sj = __shfl(s, jj); float ej = __shfl(ex, jj);
                r += ej * hx[(size_t)sj * 32 + c];
                den += ej;
            }
        }
    }
    float ro = __shfl(r, lane ^ 32);
    float do_ = __shfl(den, lane ^ 32);
    r += ro; den += do_;
    if (half == 0) {
        float al = aS[n] + aDn;
        al = al > 0.f ? al : 0.2f * al;
        float exl = __expf(al);
        float val = (r + exl * hx[(size_t)n * 32 + c]) / (den + exl) + b[c];
        out[(size_t)m * 32 + c] = val > 0.f ? val : expm1f(val);
    }
}

extern "C" void kernel_launch(void* const* d_in, const int* in_sizes, int n_in,
                              void* d_out, int out_size, void* d_ws, size_t ws_size,
                              hipStream_t stream) {
    const float* x    = (const float*)d_in[0];
    const int*   ei   = (const int*)d_in[1];
    const int*   mask = (const int*)d_in[2];
    const float* ea   = (const float*)d_in[3];
    const float* W1   = (const float*)d_in[4];
    const float* a_s1 = (const float*)d_in[5];
    const float* a_d1 = (const float*)d_in[6];
    const float* We1  = (const float*)d_in[7];
    const float* a_e1 = (const float*)d_in[8];
    const float* b1   = (const float*)d_in[9];
    const float* W2   = (const float*)d_in[10];
    const float* a_s2 = (const float*)d_in[11];
    const float* a_d2 = (const float*)d_in[12];
    const float* We2  = (const float*)d_in[13];
    const float* a_e2 = (const float*)d_in[14];
    const float* b2   = (const float*)d_in[15];
    const int* src = ei;
    const int* dst = ei + EE;
    float* out = (float*)d_out;

    char* w = (char*)d_ws;
    size_t off = 0;
    auto take = [&](size_t bytes) -> char* {
        char* p = w + off;
        off += (bytes + 255) & ~(size_t)255;
        return p;
    };
    float*  v1     = (float*)take(16 * 4);
    float*  v2     = (float*)take(16 * 4);
    float*  hx1    = (float*)take((size_t)NN * 64 * 4);
    float*  aS1    = (float*)take((size_t)NN * 4);
    float*  aD1    = (float*)take((size_t)NN * 4);
    float*  hx2    = (float*)take((size_t)NN * 32 * 4);
    float*  aS2    = (float*)take((size_t)NN * 4);
    float*  aD2    = (float*)take((size_t)NN * 4);
    int*    deg    = (int*)take((size_t)NN * 4);
    int*    rowptr = (int*)take((size_t)NN * 4);
    int*    cur    = (int*)take((size_t)NN * 4);
    int*    bcur   = (int*)take((size_t)NB * 4);
    int*    bsum   = (int*)take(64 * 4);
    float4* eSb    = (float4*)take((size_t)EE * 16);  // bucketed records; reused as h1 after consumption
    float4* eS     = (float4*)take((size_t)EE * 16);  // final dst-sorted records
    float*  h1     = (float*)eSb;                     // alias: eSb dead once k_scatter2 completes

    const int nb = (NN + 2047) / 2048;  // scan blocks

    k_v<<<1, 64, 0, stream>>>(We1, a_e1, We2, a_e2, v1, v2);
    k_node1<<<(NN + 3) / 4, 256, 0, stream>>>(x, W1, a_s1, a_d1, hx1, aS1, aD1, deg, NN);
    k_deg<<<(EE + 255) / 256, 256, 0, stream>>>(dst, deg, EE);
    k_scan1<<<nb, 256, 0, stream>>>(deg, rowptr, bsum, NN);
    k_scan2<<<1, 64, 0, stream>>>(bsum, nb);
    k_scan3<<<(NN + 255) / 256, 256, 0, stream>>>(rowptr, bsum, cur, bcur, NN);
    k_scatter1<<<(EE + 255) / 256, 256, 0, stream>>>(ea, v1, v2, src, dst, aS1, aD1, bcur, eSb, EE);
    k_scatter2<<<NB, 256, 0, stream>>>(eSb, rowptr, cur, eS, EE);
    k_agg1<<<(NN + 3) / 4, 256, 0, stream>>>(rowptr, cur, eS, hx1, aS1, aD1, b1, h1, NN);
    k_node2<<<(NN + 7) / 8, 256, 0, stream>>>(h1, W2, a_s2, a_d2, hx2, aS2, aD2, NN);
    k_agg2<<<(MM + 3) / 4, 256, 0, stream>>>(mask, rowptr, cur, eS, hx2, aS2, aD2, b2, out, MM);
}

// Round 5
// 310.864 us; speedup vs baseline: 1.7348x; 1.7348x over previous
//
#include <hip/hip_runtime.h>
#include <hip/hip_bf16.h>
#include <hip/hip_fp16.h>
#include <math.h>

#define NN 100000
#define EE 1600000
#define MM 20000

// ---- tiny: v1[16] = We1 @ a_e1 (64), v2[16] = We2 @ a_e2 (32) ----
__global__ void k_v(const float* __restrict__ We1, const float* __restrict__ ae1v,
                    const float* __restrict__ We2, const float* __restrict__ ae2v,
                    float* __restrict__ v1, float* __restrict__ v2) {
    int t = threadIdx.x;
    if (t < 16) {
        float s = 0.f;
        for (int c = 0; c < 64; ++c) s += We1[t * 64 + c] * ae1v[c];
        v1[t] = s;
    } else if (t < 32) {
        int r = t - 16;
        float s = 0.f;
        for (int c = 0; c < 32; ++c) s += We2[r * 32 + c] * ae2v[c];
        v2[r] = s;
    }
}

// ---- dst-degree histogram ----
__global__ __launch_bounds__(256) void k_deg(const int* __restrict__ dst,
                                             int* __restrict__ deg, int E) {
    int e = blockIdx.x * 256 + threadIdx.x;
    if (e < E) atomicAdd(&deg[dst[e]], 1);
}

// ---- layer-1 node transform: hx1 (fp16) = x @ W1, alpha_s/d per node; zero deg ----
__global__ __launch_bounds__(256) void k_node1(
    const float* __restrict__ x, const float* __restrict__ W,
    const float* __restrict__ a_s, const float* __restrict__ a_d,
    __half* __restrict__ hx, float* __restrict__ aS, float* __restrict__ aD,
    int* __restrict__ deg, int n_nodes)
{
    __shared__ float Wl[64 * 64];
    __shared__ float xs[4][64];
    int tid = threadIdx.x;
#pragma unroll
    for (int i = 0; i < 16; ++i) Wl[tid + i * 256] = W[tid + i * 256];
    int wv = tid >> 6, lane = tid & 63;
    int n = blockIdx.x * 4 + wv;
    bool act = (n < n_nodes);
    if (act) xs[wv][lane] = x[(size_t)n * 64 + lane];
    __syncthreads();
    if (!act) return;
    float h = 0.f;
#pragma unroll
    for (int k = 0; k < 64; ++k) h += xs[wv][k] * Wl[k * 64 + lane];
    hx[(size_t)n * 64 + lane] = __float2half(h);
    float ps = h * a_s[lane];
    float pd = h * a_d[lane];
#pragma unroll
    for (int o = 32; o > 0; o >>= 1) { ps += __shfl_xor(ps, o); pd += __shfl_xor(pd, o); }
    if (lane == 0) { aS[n] = ps; aD[n] = pd; deg[n] = 0; }
}

// ---- scan kernels: exclusive prefix over deg[0..n) (2048 elems/block) ----
__global__ __launch_bounds__(256) void k_scan1(const int* __restrict__ deg, int* __restrict__ pre,
                                               int* __restrict__ bsum, int n) {
    __shared__ int wsum[4];
    int t = threadIdx.x;
    int base = blockIdx.x * 2048 + t * 8;
    int v[8]; int s = 0;
#pragma unroll
    for (int i = 0; i < 8; ++i) { int idx = base + i; int d = (idx < n) ? deg[idx] : 0; v[i] = s; s += d; }
    int lane = t & 63, wv = t >> 6;
    int incl = s;
#pragma unroll
    for (int off = 1; off < 64; off <<= 1) { int y = __shfl_up(incl, off); if (lane >= off) incl += y; }
    if (lane == 63) wsum[wv] = incl;
    __syncthreads();
    int woff = 0;
    for (int w = 0; w < wv; ++w) woff += wsum[w];
    int texcl = woff + incl - s;
#pragma unroll
    for (int i = 0; i < 8; ++i) { int idx = base + i; if (idx < n) pre[idx] = texcl + v[i]; }
    if (t == 255) bsum[blockIdx.x] = woff + incl;
}

__global__ void k_scan2(int* __restrict__ bsum, int nb) {
    int t = threadIdx.x;
    int x = (t < nb) ? bsum[t] : 0;
    int incl = x;
    for (int off = 1; off < 64; off <<= 1) {
        int y = __shfl_up(incl, off);
        if (t >= off) incl += y;
    }
    if (t < nb) bsum[t] = incl - x;
}

__global__ void k_scan3(int* __restrict__ pre, const int* __restrict__ bsum,
                        int* __restrict__ cur, int n) {
    int i = blockIdx.x * 256 + threadIdx.x;
    if (i < n) { int r = pre[i] + bsum[i >> 11]; pre[i] = r; cur[i] = r; }
}

// ---- fused: edge dots from ea + exp(alpha1) + CSR scatter {src, ex1, ae2} ----
__global__ __launch_bounds__(256) void k_scatter(
    const float* __restrict__ ea, const float* __restrict__ v1, const float* __restrict__ v2,
    const int* __restrict__ src, const int* __restrict__ dst,
    const float* __restrict__ aS1, const float* __restrict__ aD1,
    int* __restrict__ cur, float4* __restrict__ eS, int E)
{
    int e = blockIdx.x * 256 + threadIdx.x;
    if (e >= E) return;
    const float* p = ea + (size_t)e * 16;
    float s1 = 0.f, s2 = 0.f;
#pragma unroll
    for (int i = 0; i < 16; ++i) { float t = p[i]; s1 += t * v1[i]; s2 += t * v2[i]; }
    int s = src[e], d = dst[e];
    float a = aS1[s] + aD1[d] + s1;
    a = a > 0.f ? a : 0.2f * a;
    int pos = atomicAdd(&cur[d], 1);
    eS[pos] = make_float4(__int_as_float(s), __expf(a), s2, 0.f);
}

// ---- layer-1 pull aggregation + finalize (self-loop, div, bias, elu) -> h1 ----
__global__ __launch_bounds__(256) void k_agg1(
    const int* __restrict__ rowptr, const int* __restrict__ rowend,
    const float4* __restrict__ eS, const __half* __restrict__ hx,
    const float* __restrict__ aS, const float* __restrict__ aD,
    const float* __restrict__ b, float* __restrict__ h1, int n_nodes)
{
    int wv = threadIdx.x >> 6, lane = threadIdx.x & 63;
    int n = blockIdx.x * 4 + wv;
    if (n >= n_nodes) return;
    int start = rowptr[n], end = rowend[n];
    float r = 0.f, den = 0.f;
    for (int base = start; base < end; base += 64) {
        int cnt = min(end - base, 64);
        int s = 0; float ex = 0.f;
        if (lane < cnt) {
            float4 E4 = eS[base + lane];
            s = __float_as_int(E4.x);
            ex = E4.y;
        }
        int j = 0;
        for (; j + 4 <= cnt; j += 4) {
            int s0 = __shfl(s, j), s1 = __shfl(s, j + 1), s2 = __shfl(s, j + 2), s3 = __shfl(s, j + 3);
            float e0 = __shfl(ex, j), e1 = __shfl(ex, j + 1), e2 = __shfl(ex, j + 2), e3 = __shfl(ex, j + 3);
            float h0 = __half2float(hx[(size_t)s0 * 64 + lane]);
            float h1v = __half2float(hx[(size_t)s1 * 64 + lane]);
            float h2 = __half2float(hx[(size_t)s2 * 64 + lane]);
            float h3 = __half2float(hx[(size_t)s3 * 64 + lane]);
            r += e0 * h0; r += e1 * h1v; r += e2 * h2; r += e3 * h3;
            den += e0 + e1 + e2 + e3;
        }
        for (; j < cnt; ++j) {
            int sj = __shfl(s, j); float ej = __shfl(ex, j);
            r += ej * __half2float(hx[(size_t)sj * 64 + lane]);
            den += ej;
        }
    }
    float al = aS[n] + aD[n];
    al = al > 0.f ? al : 0.2f * al;
    float exl = __expf(al);
    float hself = __half2float(hx[(size_t)n * 64 + lane]);
    float val = (r + exl * hself) / (den + exl) + b[lane];
    h1[(size_t)n * 64 + lane] = val > 0.f ? val : expm1f(val);
}

// ---- layer-2 node transform: hx2 = h1 @ W2 (64->32), alpha_s/d ----
__global__ __launch_bounds__(256) void k_node2(
    const float* __restrict__ h1, const float* __restrict__ W,
    const float* __restrict__ a_s, const float* __restrict__ a_d,
    float* __restrict__ hx, float* __restrict__ aS, float* __restrict__ aD, int n_nodes)
{
    __shared__ float Wl[64 * 32];
    __shared__ float xs[8][64];
    int tid = threadIdx.x;
#pragma unroll
    for (int i = 0; i < 8; ++i) Wl[tid + i * 256] = W[tid + i * 256];
    int n0 = blockIdx.x * 8;
    for (int i = tid; i < 8 * 64; i += 256) {
        int r = i >> 6;
        int n = n0 + r;
        xs[r][i & 63] = (n < n_nodes) ? h1[(size_t)n * 64 + (i & 63)] : 0.f;
    }
    __syncthreads();
    int g = tid >> 5, c = tid & 31;
    int n = n0 + g;
    if (n >= n_nodes) return;
    float h = 0.f;
#pragma unroll
    for (int k = 0; k < 64; ++k) h += xs[g][k] * Wl[k * 32 + c];
    hx[(size_t)n * 32 + c] = h;
    float ps = h * a_s[c], pd = h * a_d[c];
#pragma unroll
    for (int o = 16; o > 0; o >>= 1) { ps += __shfl_xor(ps, o, 32); pd += __shfl_xor(pd, o, 32); }
    if (c == 0) { aS[n] = ps; aD[n] = pd; }
}

// ---- layer-2 pull aggregation over masked nodes only + finalize -> out ----
__global__ __launch_bounds__(256) void k_agg2(
    const int* __restrict__ mask,
    const int* __restrict__ rowptr, const int* __restrict__ rowend,
    const float4* __restrict__ eS, const float* __restrict__ hx,
    const float* __restrict__ aS, const float* __restrict__ aD,
    const float* __restrict__ b, float* __restrict__ out, int m_cnt)
{
    int wv = threadIdx.x >> 6, lane = threadIdx.x & 63;
    int m = blockIdx.x * 4 + wv;
    if (m >= m_cnt) return;
    int n = mask[m];
    int start = rowptr[n], end = rowend[n];
    float aDn = aD[n];
    int half = lane >> 5, c = lane & 31;
    float r = 0.f, den = 0.f;
    for (int base = start; base < end; base += 64) {
        int cnt = min(end - base, 64);
        int s = 0; float ex = 0.f;
        if (lane < cnt) {
            float4 E4 = eS[base + lane];
            s = __float_as_int(E4.x);
            float a = aS[s] + aDn + E4.z;
            a = a > 0.f ? a : 0.2f * a;
            ex = __expf(a);
        }
        int j = 0;
        for (; j + 8 <= cnt; j += 8) {
            int j0 = j + half, j2 = j + 2 + half, j4 = j + 4 + half, j6 = j + 6 + half;
            int s0 = __shfl(s, j0), s2v = __shfl(s, j2), s4 = __shfl(s, j4), s6 = __shfl(s, j6);
            float e0 = __shfl(ex, j0), e2 = __shfl(ex, j2), e4 = __shfl(ex, j4), e6 = __shfl(ex, j6);
            r += e0 * hx[(size_t)s0 * 32 + c];
            r += e2 * hx[(size_t)s2v * 32 + c];
            r += e4 * hx[(size_t)s4 * 32 + c];
            r += e6 * hx[(size_t)s6 * 32 + c];
            den += e0 + e2 + e4 + e6;
        }
        for (; j < cnt; j += 2) {
            int jj = j + half;
            if (jj < cnt) {
                int sj = __shfl(s, jj); float ej = __shfl(ex, jj);
                r += ej * hx[(size_t)sj * 32 + c];
                den += ej;
            }
        }
    }
    float ro = __shfl(r, lane ^ 32);
    float do_ = __shfl(den, lane ^ 32);
    r += ro; den += do_;
    if (half == 0) {
        float al = aS[n] + aDn;
        al = al > 0.f ? al : 0.2f * al;
        float exl = __expf(al);
        float val = (r + exl * hx[(size_t)n * 32 + c]) / (den + exl) + b[c];
        out[(size_t)m * 32 + c] = val > 0.f ? val : expm1f(val);
    }
}

extern "C" void kernel_launch(void* const* d_in, const int* in_sizes, int n_in,
                              void* d_out, int out_size, void* d_ws, size_t ws_size,
                              hipStream_t stream) {
    const float* x    = (const float*)d_in[0];
    const int*   ei   = (const int*)d_in[1];
    const int*   mask = (const int*)d_in[2];
    const float* ea   = (const float*)d_in[3];
    const float* W1   = (const float*)d_in[4];
    const float* a_s1 = (const float*)d_in[5];
    const float* a_d1 = (const float*)d_in[6];
    const float* We1  = (const float*)d_in[7];
    const float* a_e1 = (const float*)d_in[8];
    const float* b1   = (const float*)d_in[9];
    const float* W2   = (const float*)d_in[10];
    const float* a_s2 = (const float*)d_in[11];
    const float* a_d2 = (const float*)d_in[12];
    const float* We2  = (const float*)d_in[13];
    const float* a_e2 = (const float*)d_in[14];
    const float* b2   = (const float*)d_in[15];
    const int* src = ei;
    const int* dst = ei + EE;
    float* out = (float*)d_out;

    char* w = (char*)d_ws;
    size_t off = 0;
    auto take = [&](size_t bytes) -> char* {
        char* p = w + off;
        off += (bytes + 255) & ~(size_t)255;
        return p;
    };
    float*  v1     = (float*)take(16 * 4);
    float*  v2     = (float*)take(16 * 4);
    __half* hx1h   = (__half*)take((size_t)NN * 64 * 2);
    float*  aS1    = (float*)take((size_t)NN * 4);
    float*  aD1    = (float*)take((size_t)NN * 4);
    float*  h1     = (float*)take((size_t)NN * 64 * 4);
    float*  hx2    = (float*)take((size_t)NN * 32 * 4);
    float*  aS2    = (float*)take((size_t)NN * 4);
    float*  aD2    = (float*)take((size_t)NN * 4);
    int*    deg    = (int*)take((size_t)NN * 4);
    int*    rowptr = (int*)take((size_t)NN * 4);
    int*    cur    = (int*)take((size_t)NN * 4);
    int*    bsum   = (int*)take(64 * 4);
    float4* eS     = (float4*)take((size_t)EE * 16);

    const int nb = (NN + 2047) / 2048;  // scan blocks

    k_v<<<1, 64, 0, stream>>>(We1, a_e1, We2, a_e2, v1, v2);
    k_node1<<<(NN + 3) / 4, 256, 0, stream>>>(x, W1, a_s1, a_d1, hx1h, aS1, aD1, deg, NN);
    k_deg<<<(EE + 255) / 256, 256, 0, stream>>>(dst, deg, EE);
    k_scan1<<<nb, 256, 0, stream>>>(deg, rowptr, bsum, NN);
    k_scan2<<<1, 64, 0, stream>>>(bsum, nb);
    k_scan3<<<(NN + 255) / 256, 256, 0, stream>>>(rowptr, bsum, cur, NN);
    k_scatter<<<(EE + 255) / 256, 256, 0, stream>>>(ea, v1, v2, src, dst, aS1, aD1, cur, eS, EE);
    k_agg1<<<(NN + 3) / 4, 256, 0, stream>>>(rowptr, cur, eS, hx1h, aS1, aD1, b1, h1, NN);
    k_node2<<<(NN + 7) / 8, 256, 0, stream>>>(h1, W2, a_s2, a_d2, hx2, aS2, aD2, NN);
    k_agg2<<<(MM + 3) / 4, 256, 0, stream>>>(mask, rowptr, cur, eS, hx2, aS2, aD2, b2, out, MM);
}